// Round 5
// baseline (601.100 us; speedup 1.0000x reference)
//
#include <hip/hip_runtime.h>

#define NN 50000
#define NE 800000
#define HD 64
#define NL 2
#define NT32 (NE / 32)   // 25000 edge tiles (32 edges each)
#define NT_N (NN / 16)   // 3125 node tiles
#define NCH 196          // scan chunks: 196*256 = 50176 >= NN+1

typedef __attribute__((ext_vector_type(4))) float f32x4;
typedef __attribute__((ext_vector_type(8))) short s16x8;

// ---- d_ws layout (float element offsets) ----
#define FLAG_OFF 0
#define WB_OFF   16
#define EMB_O 0
#define EW1_O 6400
#define EB1_O 22912
#define EW2_O 23040
#define EB2_O 31232
#define HW1_O 31360
#define HB1_O 47744
#define HW2_O 47872
#define HB2_O 56064
#define XW1_O 56192
#define XB1_O 64384
#define XW2_O 64512
#define XB2_O 64640
#define H_OFF    (WB_OFF + 64656)              // 64672
#define X_OFF    (H_OFF + NN * HD)
#define MAGG_OFF (X_OFF + NN * 3)
#define XAGG_OFF (MAGG_OFF + NN * HD)
#define HBF_OFF  (XAGG_OFF + NN * 3)           // ushort[NN*64]
#define CNT_OFF  (HBF_OFF + NN * 32)           // int[50176] (cnt -> cur)
#define CSUM_OFF (CNT_OFF + NCH * 256)         // int[256]
#define INCL_OFF (CSUM_OFF + 256)              // int[50176]
#define SRC_OFF  (INCL_OFF + NCH * 256)        // int[NE]
#define DST_OFF  (SRC_OFF + NE)                // int[NE]

#define ROWP 72

__device__ __forceinline__ float bf2f(unsigned short u) {
    return __uint_as_float(((unsigned int)u) << 16);
}
__device__ __forceinline__ unsigned short f2bf(float f) {
    unsigned int i = __float_as_uint(f);
    i += 0x7fffu + ((i >> 16) & 1u);
    return (unsigned short)(i >> 16);
}
__device__ __forceinline__ float silu(float v) {
    return v / (1.0f + __expf(-v));
}
__device__ __forceinline__ float ldf(const void* p, int i, int bf) {
    return bf ? bf2f(((const unsigned short*)p)[i]) : ((const float*)p)[i];
}

// -------------------------------------------------------------- detect ------
__global__ void detect_kernel(const unsigned short* __restrict__ pos, int* __restrict__ flag) {
    const int lane = threadIdx.x;
    const float v = bf2f(pos[2 * lane]);
    const float a = fabsf(v);
    const int ok = (a >= 1e-6f && a <= 1e6f) ? 1 : 0;
    const unsigned long long m = __ballot(ok);
    if (lane == 0) *flag = (__popcll(m) >= 32) ? 1 : 0;
}

// -------------------------------------------------------------- convert -----
__global__ __launch_bounds__(256) void convert_kernel(
    const void* pos, const void* emb,
    const void* ew1, const void* eb1, const void* ew2, const void* eb2,
    const void* hw1, const void* hb1, const void* hw2, const void* hb2,
    const void* xw1, const void* xb1, const void* xw2, const void* xb2,
    float* __restrict__ wbuf, float* __restrict__ x, const int* __restrict__ flag)
{
    const int bf = *flag;
    const int tid = blockIdx.x * blockDim.x + threadIdx.x;
    const int stride = gridDim.x * blockDim.x;
    for (int i = tid; i < NN * 3; i += stride) x[i] = ldf(pos, i, bf);
    for (int i = tid; i < 6400; i += stride) wbuf[EMB_O + i] = ldf(emb, i, bf);
    for (int i = tid; i < 16512; i += stride) wbuf[EW1_O + i] = ldf(ew1, i, bf);
    for (int i = tid; i < 128; i += stride) wbuf[EB1_O + i] = ldf(eb1, i, bf);
    for (int i = tid; i < 8192; i += stride) wbuf[EW2_O + i] = ldf(ew2, i, bf);
    for (int i = tid; i < 128; i += stride) wbuf[EB2_O + i] = ldf(eb2, i, bf);
    for (int i = tid; i < 16384; i += stride) wbuf[HW1_O + i] = ldf(hw1, i, bf);
    for (int i = tid; i < 128; i += stride) wbuf[HB1_O + i] = ldf(hb1, i, bf);
    for (int i = tid; i < 8192; i += stride) wbuf[HW2_O + i] = ldf(hw2, i, bf);
    for (int i = tid; i < 128; i += stride) wbuf[HB2_O + i] = ldf(hb2, i, bf);
    for (int i = tid; i < 8192; i += stride) wbuf[XW1_O + i] = ldf(xw1, i, bf);
    for (int i = tid; i < 128; i += stride) wbuf[XB1_O + i] = ldf(xb1, i, bf);
    for (int i = tid; i < 128; i += stride) wbuf[XW2_O + i] = ldf(xw2, i, bf);
    for (int i = tid; i < 2; i += stride) wbuf[XB2_O + i] = ldf(xb2, i, bf);
}

// -------------------------------------------------------------- init h ------
__global__ __launch_bounds__(256) void init_h_kernel(
    const int* __restrict__ an, const float* __restrict__ embf,
    float* __restrict__ h, unsigned short* __restrict__ h_bf)
{
    const int stride = gridDim.x * blockDim.x;
    for (int i = blockIdx.x * blockDim.x + threadIdx.x; i < NN * HD; i += stride) {
        int a = an[i >> 6];
        a = (a < 0) ? 0 : (a > 99 ? 99 : a);
        const float v = embf[a * HD + (i & 63)];
        h[i] = v;
        h_bf[i] = f2bf(v);
    }
}

// -------------------------------------------------------------- sort --------
__global__ __launch_bounds__(256) void hist_kernel(const int* __restrict__ ei, int* __restrict__ cnt) {
    const int stride = gridDim.x * blockDim.x;
    for (int e = blockIdx.x * blockDim.x + threadIdx.x; e < NE; e += stride) {
        int d = ei[NE + e];
        d = (d < 0) ? 0 : (d >= NN ? NN - 1 : d);
        atomicAdd(&cnt[d], 1);
    }
}

__global__ __launch_bounds__(256) void scan1_kernel(
    const int* __restrict__ cnt, int* __restrict__ incl, int* __restrict__ csum)
{
    __shared__ int s[256];
    const int t = threadIdx.x, b = blockIdx.x, i = b * 256 + t;
    s[t] = cnt[i];
    __syncthreads();
#pragma unroll
    for (int o = 1; o < 256; o <<= 1) {
        const int u = (t >= o) ? s[t - o] : 0;
        __syncthreads();
        s[t] += u;
        __syncthreads();
    }
    incl[i] = s[t];
    if (t == 255) csum[b] = s[255];
}

__global__ void scan2_kernel(int* __restrict__ csum) {
    __shared__ int s[256];
    const int t = threadIdx.x;
    s[t] = (t < NCH) ? csum[t] : 0;
    __syncthreads();
#pragma unroll
    for (int o = 1; o < 256; o <<= 1) {
        const int u = (t >= o) ? s[t - o] : 0;
        __syncthreads();
        s[t] += u;
        __syncthreads();
    }
    if (t < NCH) csum[t] = s[t];
}

__global__ __launch_bounds__(256) void scan3_kernel(
    int* __restrict__ cnt, const int* __restrict__ incl, const int* __restrict__ csum)
{
    const int t = threadIdx.x, b = blockIdx.x, i = b * 256 + t;
    const int off = (b > 0) ? csum[b - 1] : 0;
    cnt[i] = incl[i] - cnt[i] + off;
}

__global__ __launch_bounds__(256) void scatter_kernel(
    const int* __restrict__ ei, int* __restrict__ cur,
    int* __restrict__ src_s, int* __restrict__ dst_s)
{
    const int stride = gridDim.x * blockDim.x;
    for (int e = blockIdx.x * blockDim.x + threadIdx.x; e < NE; e += stride) {
        int s = ei[e];
        int d = ei[NE + e];
        s = (s < 0) ? 0 : (s >= NN ? NN - 1 : s);
        d = (d < 0) ? 0 : (d >= NN ? NN - 1 : d);
        const int p = atomicAdd(&cur[d], 1);
        src_s[p] = s;
        dst_s[p] = d;
    }
}

// -------------------------------------------------------------- edge MFMA ---
// One wave = 32 dst-sorted edges (2 row-blocks), software-pipelined loads,
// phi_e L2 weights in registers.
__global__ __launch_bounds__(256, 3) void edge_mfma_kernel(
    const unsigned short* __restrict__ h_bf, const float* __restrict__ x,
    const int* __restrict__ src_s, const int* __restrict__ dst_s,
    const float* __restrict__ w1, const float* __restrict__ b1,
    const float* __restrict__ w2, const float* __restrict__ b2,
    const float* __restrict__ xw1, const float* __restrict__ xb1,
    const float* __restrict__ xw2, const float* __restrict__ xb2,
    float* __restrict__ m_agg, float* __restrict__ x_agg)
{
    __shared__ unsigned short s_w1p[4 * 4 * 64 * 8];   // 16 KB
    __shared__ unsigned short s_xw1p[2 * 4 * 64 * 8];  // 8 KB
    __shared__ unsigned short s_act[4][32 * ROWP];     // 18 KB
    __shared__ float s_xd[4][32][3];                   // 1.5 KB
    __shared__ float s_wv[4][32];                      // 0.5 KB

    const int tid = threadIdx.x;
    for (int p = tid; p < 4 * 4 * 64 * 8; p += 256) {
        const int j = p & 7, ln = (p >> 3) & 63, nt = (p >> 9) & 3, kc = p >> 11;
        const int k = kc * 32 + (ln >> 4) * 8 + j, n = nt * 16 + (ln & 15);
        s_w1p[p] = f2bf(w1[k * 64 + n]);
    }
    for (int p = tid; p < 2 * 4 * 64 * 8; p += 256) {
        const int j = p & 7, ln = (p >> 3) & 63, nt = (p >> 9) & 3, kc = p >> 11;
        const int k = kc * 32 + (ln >> 4) * 8 + j, n = nt * 16 + (ln & 15);
        s_xw1p[p] = f2bf(xw1[k * 64 + n]);
    }
    __syncthreads();

    const int lane = tid & 63;
    const int wid = tid >> 6;
    const int l15 = lane & 15;
    const int q = lane >> 4;

    // phi_e layer-2 B-fragments in registers (loop-invariant)
    s16x8 bw2[2][4];
#pragma unroll
    for (int kc = 0; kc < 2; ++kc)
#pragma unroll
        for (int nt = 0; nt < 4; ++nt)
#pragma unroll
            for (int j = 0; j < 8; ++j)
                bw2[kc][nt][j] = (short)f2bf(w2[(kc * 32 + q * 8 + j) * 64 + nt * 16 + l15]);

    float b1v[4], b2v[4], xb1v[4], xw2v[4], wrv[4];
#pragma unroll
    for (int nt = 0; nt < 4; ++nt) {
        b1v[nt] = b1[nt * 16 + l15];
        b2v[nt] = b2[nt * 16 + l15];
        xb1v[nt] = xb1[nt * 16 + l15];
        xw2v[nt] = xw2[nt * 16 + l15];
        wrv[nt] = w1[128 * 64 + nt * 16 + l15];
    }
    const float xb2v = xb2[0];

    unsigned short* act = s_act[wid];
    float (*xd)[3] = s_xd[wid];
    float* wv = s_wv[wid];

    const int gwave = (blockIdx.x << 2) + wid;
    const int nwaves = gridDim.x << 2;

    // ---- prologue: load tile gwave ----
    int sid0, sid1, did0, did1;
    float ax0, ay0, az0, ax1, ay1, az1;
    s16x8 hd00, hd01, hs00, hs01, hd10, hd11, hs10, hs11;
    {
        const int e0 = gwave * 32;
        sid0 = src_s[e0 + l15];       did0 = dst_s[e0 + l15];
        sid1 = src_s[e0 + 16 + l15];  did1 = dst_s[e0 + 16 + l15];
        ax0 = x[sid0 * 3 + 0] - x[did0 * 3 + 0];
        ay0 = x[sid0 * 3 + 1] - x[did0 * 3 + 1];
        az0 = x[sid0 * 3 + 2] - x[did0 * 3 + 2];
        ax1 = x[sid1 * 3 + 0] - x[did1 * 3 + 0];
        ay1 = x[sid1 * 3 + 1] - x[did1 * 3 + 1];
        az1 = x[sid1 * 3 + 2] - x[did1 * 3 + 2];
        hd00 = *(const s16x8*)&h_bf[did0 * 64 + q * 8];
        hd01 = *(const s16x8*)&h_bf[did0 * 64 + 32 + q * 8];
        hs00 = *(const s16x8*)&h_bf[sid0 * 64 + q * 8];
        hs01 = *(const s16x8*)&h_bf[sid0 * 64 + 32 + q * 8];
        hd10 = *(const s16x8*)&h_bf[did1 * 64 + q * 8];
        hd11 = *(const s16x8*)&h_bf[did1 * 64 + 32 + q * 8];
        hs10 = *(const s16x8*)&h_bf[sid1 * 64 + q * 8];
        hs11 = *(const s16x8*)&h_bf[sid1 * 64 + 32 + q * 8];
    }

    for (int t = gwave; t < NT32; t += nwaves) {
        const int tn = t + nwaves;
        // prefetch next tile's indices (latency hidden under this tile)
        int nsid0 = 0, nsid1 = 0, ndid0 = 0, ndid1 = 0;
        if (tn < NT32) {
            const int en = tn * 32;
            nsid0 = src_s[en + l15];       ndid0 = dst_s[en + l15];
            nsid1 = src_s[en + 16 + l15];  ndid1 = dst_s[en + 16 + l15];
        }

        // stash x_diff (quads 0/1 hold the canonical copy)
        if (q == 0) { xd[l15][0] = ax0; xd[l15][1] = ay0; xd[l15][2] = az0; }
        if (q == 1) { xd[16 + l15][0] = ax1; xd[16 + l15][1] = ay1; xd[16 + l15][2] = az1; }
        const float rme0 = sqrtf(ax0 * ax0 + ay0 * ay0 + az0 * az0);
        const float rme1 = sqrtf(ax1 * ax1 + ay1 * ay1 + az1 * az1);

        // ---- phi_e layer 1: [32,128]@[128,64] ----
        f32x4 acc[2][4];
#pragma unroll
        for (int mb = 0; mb < 2; ++mb)
#pragma unroll
            for (int nt = 0; nt < 4; ++nt) acc[mb][nt] = (f32x4){0.f, 0.f, 0.f, 0.f};
#pragma unroll
        for (int kc = 0; kc < 4; ++kc) {
            const s16x8 a0 = (kc == 0) ? hd00 : (kc == 1) ? hd01 : (kc == 2) ? hs00 : hs01;
            const s16x8 a1 = (kc == 0) ? hd10 : (kc == 1) ? hd11 : (kc == 2) ? hs10 : hs11;
#pragma unroll
            for (int nt = 0; nt < 4; ++nt) {
                const s16x8 b = *(const s16x8*)&s_w1p[((kc * 4 + nt) * 64 + lane) * 8];
                acc[0][nt] = __builtin_amdgcn_mfma_f32_16x16x32_bf16(a0, b, acc[0][nt], 0, 0, 0);
                acc[1][nt] = __builtin_amdgcn_mfma_f32_16x16x32_bf16(a1, b, acc[1][nt], 0, 0, 0);
            }
        }
        float rv0[4], rv1[4];
#pragma unroll
        for (int r = 0; r < 4; ++r) {
            rv0[r] = __shfl(rme0, q * 4 + r, 64);
            rv1[r] = __shfl(rme1, q * 4 + r, 64);
        }
#pragma unroll
        for (int nt = 0; nt < 4; ++nt)
#pragma unroll
            for (int r = 0; r < 4; ++r) {
                const float v0 = silu(acc[0][nt][r] + b1v[nt] + rv0[r] * wrv[nt]);
                const float v1 = silu(acc[1][nt][r] + b1v[nt] + rv1[r] * wrv[nt]);
                act[(q * 4 + r) * ROWP + nt * 16 + l15] = f2bf(v0);
                act[(16 + q * 4 + r) * ROWP + nt * 16 + l15] = f2bf(v1);
            }

        // prefetch next tile's x-diffs (indices have arrived)
        float nax0 = 0, nay0 = 0, naz0 = 0, nax1 = 0, nay1 = 0, naz1 = 0;
        if (tn < NT32) {
            nax0 = x[nsid0 * 3 + 0] - x[ndid0 * 3 + 0];
            nay0 = x[nsid0 * 3 + 1] - x[ndid0 * 3 + 1];
            naz0 = x[nsid0 * 3 + 2] - x[ndid0 * 3 + 2];
            nax1 = x[nsid1 * 3 + 0] - x[ndid1 * 3 + 0];
            nay1 = x[nsid1 * 3 + 1] - x[ndid1 * 3 + 1];
            naz1 = x[nsid1 * 3 + 2] - x[ndid1 * 3 + 2];
        }

        // ---- phi_e layer 2 (B in registers) ----
        f32x4 acc2[2][4];
#pragma unroll
        for (int mb = 0; mb < 2; ++mb)
#pragma unroll
            for (int nt = 0; nt < 4; ++nt) acc2[mb][nt] = (f32x4){0.f, 0.f, 0.f, 0.f};
#pragma unroll
        for (int kc = 0; kc < 2; ++kc) {
            const s16x8 a0 = *(const s16x8*)&act[l15 * ROWP + kc * 32 + q * 8];
            const s16x8 a1 = *(const s16x8*)&act[(16 + l15) * ROWP + kc * 32 + q * 8];
#pragma unroll
            for (int nt = 0; nt < 4; ++nt) {
                acc2[0][nt] = __builtin_amdgcn_mfma_f32_16x16x32_bf16(a0, bw2[kc][nt], acc2[0][nt], 0, 0, 0);
                acc2[1][nt] = __builtin_amdgcn_mfma_f32_16x16x32_bf16(a1, bw2[kc][nt], acc2[1][nt], 0, 0, 0);
            }
        }
#pragma unroll
        for (int nt = 0; nt < 4; ++nt)
#pragma unroll
            for (int r = 0; r < 4; ++r) {
                const float v0 = silu(acc2[0][nt][r] + b2v[nt]);
                const float v1 = silu(acc2[1][nt][r] + b2v[nt]);
                act[(q * 4 + r) * ROWP + nt * 16 + l15] = f2bf(v0);
                act[(16 + q * 4 + r) * ROWP + nt * 16 + l15] = f2bf(v1);
            }

        // prefetch next tile's h-fragments
        s16x8 nhd00 = {}, nhd01 = {}, nhs00 = {}, nhs01 = {};
        s16x8 nhd10 = {}, nhd11 = {}, nhs10 = {}, nhs11 = {};
        if (tn < NT32) {
            nhd00 = *(const s16x8*)&h_bf[ndid0 * 64 + q * 8];
            nhd01 = *(const s16x8*)&h_bf[ndid0 * 64 + 32 + q * 8];
            nhs00 = *(const s16x8*)&h_bf[nsid0 * 64 + q * 8];
            nhs01 = *(const s16x8*)&h_bf[nsid0 * 64 + 32 + q * 8];
            nhd10 = *(const s16x8*)&h_bf[ndid1 * 64 + q * 8];
            nhd11 = *(const s16x8*)&h_bf[ndid1 * 64 + 32 + q * 8];
            nhs10 = *(const s16x8*)&h_bf[nsid1 * 64 + q * 8];
            nhs11 = *(const s16x8*)&h_bf[nsid1 * 64 + 32 + q * 8];
        }

        // ---- phi_x layer 1 ----
        f32x4 xacc[2][4];
#pragma unroll
        for (int mb = 0; mb < 2; ++mb)
#pragma unroll
            for (int nt = 0; nt < 4; ++nt) xacc[mb][nt] = (f32x4){0.f, 0.f, 0.f, 0.f};
#pragma unroll
        for (int kc = 0; kc < 2; ++kc) {
            const s16x8 a0 = *(const s16x8*)&act[l15 * ROWP + kc * 32 + q * 8];
            const s16x8 a1 = *(const s16x8*)&act[(16 + l15) * ROWP + kc * 32 + q * 8];
#pragma unroll
            for (int nt = 0; nt < 4; ++nt) {
                const s16x8 b = *(const s16x8*)&s_xw1p[((kc * 4 + nt) * 64 + lane) * 8];
                xacc[0][nt] = __builtin_amdgcn_mfma_f32_16x16x32_bf16(a0, b, xacc[0][nt], 0, 0, 0);
                xacc[1][nt] = __builtin_amdgcn_mfma_f32_16x16x32_bf16(a1, b, xacc[1][nt], 0, 0, 0);
            }
        }
        // ---- phi_x layer 2: per-edge scalar ----
#pragma unroll
        for (int mb = 0; mb < 2; ++mb) {
            float ssum[4];
#pragma unroll
            for (int r = 0; r < 4; ++r) {
                float s = 0.f;
#pragma unroll
                for (int nt = 0; nt < 4; ++nt)
                    s += silu(xacc[mb][nt][r] + xb1v[nt]) * xw2v[nt];
                ssum[r] = s;
            }
#pragma unroll
            for (int off = 1; off < 16; off <<= 1)
#pragma unroll
                for (int r = 0; r < 4; ++r) ssum[r] += __shfl_xor(ssum[r], off, 64);
            if (l15 == 0) {
#pragma unroll
                for (int r = 0; r < 4; ++r) wv[mb * 16 + q * 4 + r] = ssum[r] + xb2v;
            }
        }

        // ---- segmented per-dst aggregation ----
        int dstv[33];
#pragma unroll
        for (int rr = 0; rr < 16; ++rr) dstv[rr] = __shfl(did0, rr, 64);
#pragma unroll
        for (int rr = 0; rr < 16; ++rr) dstv[16 + rr] = __shfl(did1, rr, 64);
        dstv[32] = -1;

        float macc = 0.f;
#pragma unroll
        for (int rr = 0; rr < 32; ++rr) {
            macc += bf2f(act[rr * ROWP + lane]);
            if (dstv[rr + 1] != dstv[rr]) {
                atomicAdd(&m_agg[dstv[rr] * 64 + lane], macc);
                macc = 0.f;
            }
        }
        if (lane < 3) {
            float xac = 0.f;
#pragma unroll
            for (int rr = 0; rr < 32; ++rr) {
                xac += wv[rr] * xd[rr][lane];
                if (dstv[rr + 1] != dstv[rr]) {
                    atomicAdd(&x_agg[dstv[rr] * 3 + lane], xac);
                    xac = 0.f;
                }
            }
        }

        // rotate pipeline registers
        sid0 = nsid0; sid1 = nsid1; did0 = ndid0; did1 = ndid1;
        ax0 = nax0; ay0 = nay0; az0 = naz0; ax1 = nax1; ay1 = nay1; az1 = naz1;
        hd00 = nhd00; hd01 = nhd01; hs00 = nhs00; hs01 = nhs01;
        hd10 = nhd10; hd11 = nhd11; hs10 = nhs10; hs11 = nhs11;
    }
}

// -------------------------------------------------------------- node MFMA ---
__global__ __launch_bounds__(256) void node_mfma_kernel(
    float* __restrict__ h, float* __restrict__ x,
    const float* __restrict__ m_agg, const float* __restrict__ x_agg,
    const float* __restrict__ w1, const float* __restrict__ b1,   // [128][64]
    const float* __restrict__ w2, const float* __restrict__ b2,   // [64][64]
    unsigned short* __restrict__ h_bf,
    void* __restrict__ outv, const int* __restrict__ flag)
{
    __shared__ unsigned short s_w1p[4 * 4 * 64 * 8];   // 16 KB
    __shared__ unsigned short s_w2p[2 * 4 * 64 * 8];   // 8 KB
    __shared__ unsigned short s_act[4][16 * ROWP];     // 9 KB

    const int tid = threadIdx.x;
    for (int p = tid; p < 4 * 4 * 64 * 8; p += 256) {
        const int j = p & 7, ln = (p >> 3) & 63, nt = (p >> 9) & 3, kc = p >> 11;
        const int k = kc * 32 + (ln >> 4) * 8 + j, n = nt * 16 + (ln & 15);
        s_w1p[p] = f2bf(w1[k * 64 + n]);
    }
    for (int p = tid; p < 2 * 4 * 64 * 8; p += 256) {
        const int j = p & 7, ln = (p >> 3) & 63, nt = (p >> 9) & 3, kc = p >> 11;
        const int k = kc * 32 + (ln >> 4) * 8 + j, n = nt * 16 + (ln & 15);
        s_w2p[p] = f2bf(w2[k * 64 + n]);
    }
    __syncthreads();

    const int bf = flag ? *flag : 1;

    for (int i = blockIdx.x * 256 + tid; i < NN * 3; i += gridDim.x * 256) {
        const float xn = x[i] + x_agg[i];
        x[i] = xn;
        if (outv) {
            if (bf) ((unsigned short*)outv)[NN * HD + i] = f2bf(xn);
            else ((float*)outv)[NN * HD + i] = xn;
        }
    }

    const int lane = tid & 63;
    const int wid = tid >> 6;
    const int l15 = lane & 15;
    const int q = lane >> 4;

    float b1v[4], b2v[4];
#pragma unroll
    for (int nt = 0; nt < 4; ++nt) {
        b1v[nt] = b1[nt * 16 + l15];
        b2v[nt] = b2[nt * 16 + l15];
    }
    unsigned short* act = s_act[wid];

    for (int t = (blockIdx.x << 2) + wid; t < NT_N; t += gridDim.x << 2) {
        const int n = t * 16 + l15;
        const s16x8 a0 = *(const s16x8*)&h_bf[n * 64 + q * 8];
        const s16x8 a1 = *(const s16x8*)&h_bf[n * 64 + 32 + q * 8];
        const f32x4 m0 = *(const f32x4*)&m_agg[n * 64 + q * 8];
        const f32x4 m1 = *(const f32x4*)&m_agg[n * 64 + q * 8 + 4];
        const f32x4 m2 = *(const f32x4*)&m_agg[n * 64 + 32 + q * 8];
        const f32x4 m3 = *(const f32x4*)&m_agg[n * 64 + 32 + q * 8 + 4];
        s16x8 a2, a3;
#pragma unroll
        for (int j = 0; j < 4; ++j) {
            a2[j] = (short)f2bf(m0[j]); a2[4 + j] = (short)f2bf(m1[j]);
            a3[j] = (short)f2bf(m2[j]); a3[4 + j] = (short)f2bf(m3[j]);
        }

        f32x4 acc[4];
#pragma unroll
        for (int nt = 0; nt < 4; ++nt) acc[nt] = (f32x4){0.f, 0.f, 0.f, 0.f};
#pragma unroll
        for (int kc = 0; kc < 4; ++kc) {
            const s16x8 a = (kc == 0) ? a0 : (kc == 1) ? a1 : (kc == 2) ? a2 : a3;
#pragma unroll
            for (int nt = 0; nt < 4; ++nt) {
                const s16x8 b = *(const s16x8*)&s_w1p[((kc * 4 + nt) * 64 + lane) * 8];
                acc[nt] = __builtin_amdgcn_mfma_f32_16x16x32_bf16(a, b, acc[nt], 0, 0, 0);
            }
        }
#pragma unroll
        for (int nt = 0; nt < 4; ++nt)
#pragma unroll
            for (int r = 0; r < 4; ++r)
                act[(q * 4 + r) * ROWP + nt * 16 + l15] = f2bf(silu(acc[nt][r] + b1v[nt]));

        f32x4 acc2[4];
#pragma unroll
        for (int nt = 0; nt < 4; ++nt) acc2[nt] = (f32x4){0.f, 0.f, 0.f, 0.f};
#pragma unroll
        for (int kc = 0; kc < 2; ++kc) {
            const s16x8 a = *(const s16x8*)&act[l15 * ROWP + kc * 32 + q * 8];
#pragma unroll
            for (int nt = 0; nt < 4; ++nt) {
                const s16x8 b = *(const s16x8*)&s_w2p[((kc * 4 + nt) * 64 + lane) * 8];
                acc2[nt] = __builtin_amdgcn_mfma_f32_16x16x32_bf16(a, b, acc2[nt], 0, 0, 0);
            }
        }
#pragma unroll
        for (int nt = 0; nt < 4; ++nt)
#pragma unroll
            for (int r = 0; r < 4; ++r) {
                const int row = t * 16 + q * 4 + r, col = nt * 16 + l15;
                const float hn = h[row * 64 + col] + acc2[nt][r] + b2v[nt];
                h[row * 64 + col] = hn;
                h_bf[row * 64 + col] = f2bf(hn);
                if (outv) {
                    if (bf) ((unsigned short*)outv)[row * 64 + col] = f2bf(hn);
                    else ((float*)outv)[row * 64 + col] = hn;
                }
            }
    }
}

// -------------------------------------------------------------- launch ------
extern "C" void kernel_launch(void* const* d_in, const int* in_sizes, int n_in,
                              void* d_out, int out_size, void* d_ws, size_t ws_size,
                              hipStream_t stream) {
    const int* an = (const int*)d_in[0];
    const void* pos = d_in[1];
    const int* ei = (const int*)d_in[2];

    int wi = 4;
    if (n_in > 4 && in_sizes[4] == 6400) wi = 4;
    else if (n_in > 3 && in_sizes[3] == 6400) wi = 3;
    const void* emb = d_in[wi];
    const void* e_w1 = d_in[wi + 1];
    const void* e_b1 = d_in[wi + 2];
    const void* e_w2 = d_in[wi + 3];
    const void* e_b2 = d_in[wi + 4];
    const void* h_w1 = d_in[wi + 5];
    const void* h_b1 = d_in[wi + 6];
    const void* h_w2 = d_in[wi + 7];
    const void* h_b2 = d_in[wi + 8];
    const void* x_w1 = d_in[wi + 9];
    const void* x_b1 = d_in[wi + 10];
    const void* x_w2 = d_in[wi + 11];
    const void* x_b2 = d_in[wi + 12];

    float* ws = (float*)d_ws;
    int* flag = (int*)(ws + FLAG_OFF);
    float* wbuf = ws + WB_OFF;
    float* h = ws + H_OFF;
    float* x = ws + X_OFF;
    float* m_agg = ws + MAGG_OFF;
    float* x_agg = ws + XAGG_OFF;
    unsigned short* h_bf = (unsigned short*)(ws + HBF_OFF);
    int* cnt = (int*)(ws + CNT_OFF);
    int* csum = (int*)(ws + CSUM_OFF);
    int* incl = (int*)(ws + INCL_OFF);
    int* src_s = (int*)(ws + SRC_OFF);
    int* dst_s = (int*)(ws + DST_OFF);

    detect_kernel<<<1, 64, 0, stream>>>((const unsigned short*)pos, flag);
    convert_kernel<<<256, 256, 0, stream>>>(pos, emb,
        e_w1, e_b1, e_w2, e_b2, h_w1, h_b1, h_w2, h_b2,
        x_w1, x_b1, x_w2, x_b2, wbuf, x, flag);
    init_h_kernel<<<784, 256, 0, stream>>>(an, wbuf + EMB_O, h, h_bf);

    hipMemsetAsync(cnt, 0, NCH * 256 * sizeof(int), stream);
    hist_kernel<<<512, 256, 0, stream>>>(ei, cnt);
    scan1_kernel<<<NCH, 256, 0, stream>>>(cnt, incl, csum);
    scan2_kernel<<<1, 256, 0, stream>>>(csum);
    scan3_kernel<<<NCH, 256, 0, stream>>>(cnt, incl, csum);
    scatter_kernel<<<512, 256, 0, stream>>>(ei, cnt, src_s, dst_s);

    for (int l = 0; l < NL; ++l) {
        hipMemsetAsync(m_agg, 0, (size_t)NN * HD * sizeof(float), stream);
        hipMemsetAsync(x_agg, 0, (size_t)NN * 3 * sizeof(float), stream);

        edge_mfma_kernel<<<1024, 256, 0, stream>>>(h_bf, x, src_s, dst_s,
            wbuf + EW1_O + l * 129 * 64, wbuf + EB1_O + l * 64,
            wbuf + EW2_O + l * 64 * 64, wbuf + EB2_O + l * 64,
            wbuf + XW1_O + l * 64 * 64, wbuf + XB1_O + l * 64,
            wbuf + XW2_O + l * 64, wbuf + XB2_O + l,
            m_agg, x_agg);

        void* out_p = (l == NL - 1) ? d_out : nullptr;
        node_mfma_kernel<<<782, 256, 0, stream>>>(h, x, m_agg, x_agg,
            wbuf + HW1_O + l * 128 * 64, wbuf + HB1_O + l * 64,
            wbuf + HW2_O + l * 64 * 64, wbuf + HB2_O + l * 64,
            h_bf, out_p, flag);
    }
}

// Round 6
// 448.233 us; speedup vs baseline: 1.3410x; 1.3410x over previous
//
#include <hip/hip_runtime.h>

#define NN 50000
#define NE 800000
#define HD 64
#define NL 2
#define NT_E (NE / 16)   // 50000 edge tiles
#define NT_N (NN / 16)   // 3125 node tiles
#define NCH 196          // scan chunks: 196*256 = 50176 >= NN+1

typedef __attribute__((ext_vector_type(4))) float f32x4;
typedef __attribute__((ext_vector_type(8))) short s16x8;

// ---- d_ws layout (float element offsets) ----
#define FLAG_OFF 0
#define WB_OFF   16
#define EMB_O 0
#define EW1_O 6400
#define EB1_O 22912
#define EW2_O 23040
#define EB2_O 31232
#define HW1_O 31360
#define HB1_O 47744
#define HW2_O 47872
#define HB2_O 56064
#define XW1_O 56192
#define XB1_O 64384
#define XW2_O 64512
#define XB2_O 64640
#define X_OFF    (WB_OFF + 64656)              // fp32 x, padded [NN][4]
#define MAGG_OFF (X_OFF + NN * 4)
#define XAGG_OFF (MAGG_OFF + NN * HD)
#define HBF_OFF  (XAGG_OFF + NN * 3)           // ushort[NN*64]
#define CNT_OFF  (HBF_OFF + NN * 32)
#define CSUM_OFF (CNT_OFF + NCH * 256)
#define INCL_OFF (CSUM_OFF + 256)
#define PAIR_OFF (INCL_OFF + NCH * 256)        // int2[NE]

#define ROWP 72

__device__ __forceinline__ float bf2f(unsigned short u) {
    return __uint_as_float(((unsigned int)u) << 16);
}
__device__ __forceinline__ unsigned short f2bf(float f) {      // RNE (outputs)
    unsigned int i = __float_as_uint(f);
    i += 0x7fffu + ((i >> 16) & 1u);
    return (unsigned short)(i >> 16);
}
__device__ __forceinline__ unsigned short f2bf_t(float f) {    // trunc (LDS temps)
    return (unsigned short)(__float_as_uint(f) >> 16);
}
__device__ __forceinline__ float silu(float v) {               // no div sequence
    const float e = __expf(-v);
    return v * __builtin_amdgcn_rcpf(1.0f + e);
}
__device__ __forceinline__ float ldf(const void* p, int i, int bf) {
    return bf ? bf2f(((const unsigned short*)p)[i]) : ((const float*)p)[i];
}

// -------------------------------------------------------------- detect ------
__global__ void detect_kernel(const unsigned short* __restrict__ pos, int* __restrict__ flag) {
    const int lane = threadIdx.x;
    const float v = bf2f(pos[2 * lane]);
    const float a = fabsf(v);
    const int ok = (a >= 1e-6f && a <= 1e6f) ? 1 : 0;
    const unsigned long long m = __ballot(ok);
    if (lane == 0) *flag = (__popcll(m) >= 32) ? 1 : 0;
}

// -------------------------------------------------------------- convert -----
__global__ __launch_bounds__(256) void convert_kernel(
    const void* pos, const void* emb,
    const void* ew1, const void* eb1, const void* ew2, const void* eb2,
    const void* hw1, const void* hb1, const void* hw2, const void* hb2,
    const void* xw1, const void* xb1, const void* xw2, const void* xb2,
    float* __restrict__ wbuf, float* __restrict__ x, const int* __restrict__ flag)
{
    const int bf = *flag;
    const int tid = blockIdx.x * blockDim.x + threadIdx.x;
    const int stride = gridDim.x * blockDim.x;
    for (int n = tid; n < NN; n += stride) {
        x[n * 4 + 0] = ldf(pos, n * 3 + 0, bf);
        x[n * 4 + 1] = ldf(pos, n * 3 + 1, bf);
        x[n * 4 + 2] = ldf(pos, n * 3 + 2, bf);
        x[n * 4 + 3] = 0.f;
    }
    for (int i = tid; i < 6400; i += stride) wbuf[EMB_O + i] = ldf(emb, i, bf);
    for (int i = tid; i < 16512; i += stride) wbuf[EW1_O + i] = ldf(ew1, i, bf);
    for (int i = tid; i < 128; i += stride) wbuf[EB1_O + i] = ldf(eb1, i, bf);
    for (int i = tid; i < 8192; i += stride) wbuf[EW2_O + i] = ldf(ew2, i, bf);
    for (int i = tid; i < 128; i += stride) wbuf[EB2_O + i] = ldf(eb2, i, bf);
    for (int i = tid; i < 16384; i += stride) wbuf[HW1_O + i] = ldf(hw1, i, bf);
    for (int i = tid; i < 128; i += stride) wbuf[HB1_O + i] = ldf(hb1, i, bf);
    for (int i = tid; i < 8192; i += stride) wbuf[HW2_O + i] = ldf(hw2, i, bf);
    for (int i = tid; i < 128; i += stride) wbuf[HB2_O + i] = ldf(hb2, i, bf);
    for (int i = tid; i < 8192; i += stride) wbuf[XW1_O + i] = ldf(xw1, i, bf);
    for (int i = tid; i < 128; i += stride) wbuf[XB1_O + i] = ldf(xb1, i, bf);
    for (int i = tid; i < 128; i += stride) wbuf[XW2_O + i] = ldf(xw2, i, bf);
    for (int i = tid; i < 2; i += stride) wbuf[XB2_O + i] = ldf(xb2, i, bf);
}

// -------------------------------------------------------------- init h ------
__global__ __launch_bounds__(256) void init_h_kernel(
    const int* __restrict__ an, const float* __restrict__ embf,
    unsigned short* __restrict__ h_bf)
{
    const int stride = gridDim.x * blockDim.x;
    for (int i = blockIdx.x * blockDim.x + threadIdx.x; i < NN * HD; i += stride) {
        int a = an[i >> 6];
        a = (a < 0) ? 0 : (a > 99 ? 99 : a);
        h_bf[i] = f2bf(embf[a * HD + (i & 63)]);
    }
}

// -------------------------------------------------------------- sort --------
__global__ __launch_bounds__(256) void hist_kernel(const int* __restrict__ ei, int* __restrict__ cnt) {
    const int stride = gridDim.x * blockDim.x;
    for (int e = blockIdx.x * blockDim.x + threadIdx.x; e < NE; e += stride) {
        int d = ei[NE + e];
        d = (d < 0) ? 0 : (d >= NN ? NN - 1 : d);
        atomicAdd(&cnt[d], 1);
    }
}

__global__ __launch_bounds__(256) void scan1_kernel(
    const int* __restrict__ cnt, int* __restrict__ incl, int* __restrict__ csum)
{
    __shared__ int s[256];
    const int t = threadIdx.x, b = blockIdx.x, i = b * 256 + t;
    s[t] = cnt[i];
    __syncthreads();
#pragma unroll
    for (int o = 1; o < 256; o <<= 1) {
        const int u = (t >= o) ? s[t - o] : 0;
        __syncthreads();
        s[t] += u;
        __syncthreads();
    }
    incl[i] = s[t];
    if (t == 255) csum[b] = s[255];
}

__global__ void scan2_kernel(int* __restrict__ csum) {
    __shared__ int s[256];
    const int t = threadIdx.x;
    s[t] = (t < NCH) ? csum[t] : 0;
    __syncthreads();
#pragma unroll
    for (int o = 1; o < 256; o <<= 1) {
        const int u = (t >= o) ? s[t - o] : 0;
        __syncthreads();
        s[t] += u;
        __syncthreads();
    }
    if (t < NCH) csum[t] = s[t];
}

__global__ __launch_bounds__(256) void scan3_kernel(
    int* __restrict__ cnt, const int* __restrict__ incl, const int* __restrict__ csum)
{
    const int t = threadIdx.x, b = blockIdx.x, i = b * 256 + t;
    const int off = (b > 0) ? csum[b - 1] : 0;
    cnt[i] = incl[i] - cnt[i] + off;
}

__global__ __launch_bounds__(256) void scatter_kernel(
    const int* __restrict__ ei, int* __restrict__ cur, int2* __restrict__ pair)
{
    const int stride = gridDim.x * blockDim.x;
    for (int e = blockIdx.x * blockDim.x + threadIdx.x; e < NE; e += stride) {
        int s = ei[e];
        int d = ei[NE + e];
        s = (s < 0) ? 0 : (s >= NN ? NN - 1 : s);
        d = (d < 0) ? 0 : (d >= NN ? NN - 1 : d);
        const int p = atomicAdd(&cur[d], 1);
        pair[p] = make_int2(s, d);
    }
}

// -------------------------------------------------------------- edge MFMA ---
// One wave = 16 dst-sorted edges; w2 B-frags in registers; fast silu; trunc
// bf16 stores for LDS temps. LDS ~35 KB -> 4 blocks/CU.
__global__ __launch_bounds__(256, 4) void edge_mfma_kernel(
    const unsigned short* __restrict__ h_bf, const float* __restrict__ x,
    const int2* __restrict__ pair,
    const float* __restrict__ w1, const float* __restrict__ b1,
    const float* __restrict__ b2,
    const float* __restrict__ w2,
    const float* __restrict__ xw1, const float* __restrict__ xb1,
    const float* __restrict__ xw2, const float* __restrict__ xb2,
    float* __restrict__ m_agg, float* __restrict__ x_agg)
{
    __shared__ unsigned short s_w1p[4 * 4 * 64 * 8];   // 16 KB
    __shared__ unsigned short s_xw1p[2 * 4 * 64 * 8];  // 8 KB
    __shared__ unsigned short s_act[4][16 * ROWP];     // 9 KB
    __shared__ float s_xd[4][16][4];                   // 1 KB
    __shared__ float s_wv[4][16];                      // 256 B

    const int tid = threadIdx.x;
    for (int p = tid; p < 4 * 4 * 64 * 8; p += 256) {
        const int j = p & 7, ln = (p >> 3) & 63, nt = (p >> 9) & 3, kc = p >> 11;
        const int k = kc * 32 + (ln >> 4) * 8 + j, n = nt * 16 + (ln & 15);
        s_w1p[p] = f2bf(w1[k * 64 + n]);
    }
    for (int p = tid; p < 2 * 4 * 64 * 8; p += 256) {
        const int j = p & 7, ln = (p >> 3) & 63, nt = (p >> 9) & 3, kc = p >> 11;
        const int k = kc * 32 + (ln >> 4) * 8 + j, n = nt * 16 + (ln & 15);
        s_xw1p[p] = f2bf(xw1[k * 64 + n]);
    }
    __syncthreads();

    const int lane = tid & 63;
    const int wid = tid >> 6;
    const int l15 = lane & 15;
    const int q = lane >> 4;

    // phi_e layer-2 B-fragments in registers (loop-invariant)
    s16x8 bw2[2][4];
#pragma unroll
    for (int kc = 0; kc < 2; ++kc)
#pragma unroll
        for (int nt = 0; nt < 4; ++nt)
#pragma unroll
            for (int j = 0; j < 8; ++j)
                bw2[kc][nt][j] = (short)f2bf(w2[(kc * 32 + q * 8 + j) * 64 + nt * 16 + l15]);

    float b1v[4], b2v[4], xb1v[4], xw2v[4], wrv[4];
#pragma unroll
    for (int nt = 0; nt < 4; ++nt) {
        b1v[nt] = b1[nt * 16 + l15];
        b2v[nt] = b2[nt * 16 + l15];
        xb1v[nt] = xb1[nt * 16 + l15];
        xw2v[nt] = xw2[nt * 16 + l15];
        wrv[nt] = w1[128 * 64 + nt * 16 + l15];
    }
    const float xb2v = xb2[0];

    unsigned short* act = s_act[wid];
    float (*xd)[4] = s_xd[wid];
    float* wv = s_wv[wid];

    const int gwave = (blockIdx.x << 2) + wid;
    const int nwaves = gridDim.x << 2;

    for (int t = gwave; t < NT_E; t += nwaves) {
        const int e0 = t * 16;
        const int2 e = pair[e0 + l15];
        const int sidx = e.x, didx = e.y;
        const f32x4 xs = *(const f32x4*)&x[sidx * 4];
        const f32x4 xdv = *(const f32x4*)&x[didx * 4];
        const float ax = xs[0] - xdv[0];
        const float ay = xs[1] - xdv[1];
        const float az = xs[2] - xdv[2];
        const float rme = sqrtf(ax * ax + ay * ay + az * az);
        if (lane < 16) { xd[lane][0] = ax; xd[lane][1] = ay; xd[lane][2] = az; }

        const s16x8 a_hd0 = *(const s16x8*)&h_bf[didx * 64 + q * 8];
        const s16x8 a_hd1 = *(const s16x8*)&h_bf[didx * 64 + 32 + q * 8];
        const s16x8 a_hs0 = *(const s16x8*)&h_bf[sidx * 64 + q * 8];
        const s16x8 a_hs1 = *(const s16x8*)&h_bf[sidx * 64 + 32 + q * 8];

        // ---- phi_e layer 1 ----
        f32x4 acc[4];
#pragma unroll
        for (int nt = 0; nt < 4; ++nt) acc[nt] = (f32x4){0.f, 0.f, 0.f, 0.f};
#pragma unroll
        for (int kc = 0; kc < 4; ++kc) {
            const s16x8 a = (kc == 0) ? a_hd0 : (kc == 1) ? a_hd1 : (kc == 2) ? a_hs0 : a_hs1;
#pragma unroll
            for (int nt = 0; nt < 4; ++nt) {
                const s16x8 b = *(const s16x8*)&s_w1p[((kc * 4 + nt) * 64 + lane) * 8];
                acc[nt] = __builtin_amdgcn_mfma_f32_16x16x32_bf16(a, b, acc[nt], 0, 0, 0);
            }
        }
        float rv[4];
#pragma unroll
        for (int r = 0; r < 4; ++r) rv[r] = __shfl(rme, q * 4 + r, 64);
#pragma unroll
        for (int nt = 0; nt < 4; ++nt)
#pragma unroll
            for (int r = 0; r < 4; ++r) {
                const float v = silu(acc[nt][r] + b1v[nt] + rv[r] * wrv[nt]);
                act[(q * 4 + r) * ROWP + nt * 16 + l15] = f2bf_t(v);
            }

        // ---- phi_e layer 2 (B in registers) -> m ----
        f32x4 acc2[4];
#pragma unroll
        for (int nt = 0; nt < 4; ++nt) acc2[nt] = (f32x4){0.f, 0.f, 0.f, 0.f};
#pragma unroll
        for (int kc = 0; kc < 2; ++kc) {
            const s16x8 a = *(const s16x8*)&act[l15 * ROWP + kc * 32 + q * 8];
#pragma unroll
            for (int nt = 0; nt < 4; ++nt)
                acc2[nt] = __builtin_amdgcn_mfma_f32_16x16x32_bf16(a, bw2[kc][nt], acc2[nt], 0, 0, 0);
        }
#pragma unroll
        for (int nt = 0; nt < 4; ++nt)
#pragma unroll
            for (int r = 0; r < 4; ++r) {
                const float v = silu(acc2[nt][r] + b2v[nt]);
                act[(q * 4 + r) * ROWP + nt * 16 + l15] = f2bf_t(v);
            }

        // ---- phi_x layer 1 ----
        f32x4 xacc[4];
#pragma unroll
        for (int nt = 0; nt < 4; ++nt) xacc[nt] = (f32x4){0.f, 0.f, 0.f, 0.f};
#pragma unroll
        for (int kc = 0; kc < 2; ++kc) {
            const s16x8 a = *(const s16x8*)&act[l15 * ROWP + kc * 32 + q * 8];
#pragma unroll
            for (int nt = 0; nt < 4; ++nt) {
                const s16x8 b = *(const s16x8*)&s_xw1p[((kc * 4 + nt) * 64 + lane) * 8];
                xacc[nt] = __builtin_amdgcn_mfma_f32_16x16x32_bf16(a, b, xacc[nt], 0, 0, 0);
            }
        }
        // ---- phi_x layer 2 ----
        float ssum[4];
#pragma unroll
        for (int r = 0; r < 4; ++r) {
            float s = 0.f;
#pragma unroll
            for (int nt = 0; nt < 4; ++nt)
                s += silu(xacc[nt][r] + xb1v[nt]) * xw2v[nt];
            ssum[r] = s;
        }
#pragma unroll
        for (int off = 1; off < 16; off <<= 1)
#pragma unroll
            for (int r = 0; r < 4; ++r) ssum[r] += __shfl_xor(ssum[r], off, 64);
        if (l15 == 0) {
#pragma unroll
            for (int r = 0; r < 4; ++r) wv[q * 4 + r] = ssum[r] + xb2v;
        }

        // ---- segmented per-dst aggregation ----
        int dstv[17];
#pragma unroll
        for (int rr = 0; rr < 16; ++rr) dstv[rr] = __shfl(didx, rr, 64);
        dstv[16] = -1;

        float macc = 0.f;
#pragma unroll
        for (int rr = 0; rr < 16; ++rr) {
            macc += bf2f(act[rr * ROWP + lane]);
            if (dstv[rr + 1] != dstv[rr]) {
                atomicAdd(&m_agg[dstv[rr] * 64 + lane], macc);
                macc = 0.f;
            }
        }
        if (lane < 3) {
            float xac = 0.f;
#pragma unroll
            for (int rr = 0; rr < 16; ++rr) {
                xac += wv[rr] * xd[rr][lane];
                if (dstv[rr + 1] != dstv[rr]) {
                    atomicAdd(&x_agg[dstv[rr] * 3 + lane], xac);
                    xac = 0.f;
                }
            }
        }
    }
}

// -------------------------------------------------------------- node MFMA ---
// h kept bf16-only (residual in bf16); w2 in registers; fast silu.
__global__ __launch_bounds__(256, 4) void node_mfma_kernel(
    float* __restrict__ x,
    const float* __restrict__ m_agg, const float* __restrict__ x_agg,
    const float* __restrict__ w1, const float* __restrict__ b1,   // [128][64]
    const float* __restrict__ w2, const float* __restrict__ b2,   // [64][64]
    unsigned short* __restrict__ h_bf,
    void* __restrict__ outv, const int* __restrict__ flag)
{
    __shared__ unsigned short s_w1p[4 * 4 * 64 * 8];   // 16 KB
    __shared__ unsigned short s_act[4][16 * ROWP];     // 9 KB

    const int tid = threadIdx.x;
    for (int p = tid; p < 4 * 4 * 64 * 8; p += 256) {
        const int j = p & 7, ln = (p >> 3) & 63, nt = (p >> 9) & 3, kc = p >> 11;
        const int k = kc * 32 + (ln >> 4) * 8 + j, n = nt * 16 + (ln & 15);
        s_w1p[p] = f2bf(w1[k * 64 + n]);
    }
    __syncthreads();

    const int bf = flag ? *flag : 1;
    const int lane = tid & 63;
    const int wid = tid >> 6;
    const int l15 = lane & 15;
    const int q = lane >> 4;

    // x update (+ optional out)
    for (int n = blockIdx.x * 256 + tid; n < NN; n += gridDim.x * 256) {
#pragma unroll
        for (int c = 0; c < 3; ++c) {
            const float xn = x[n * 4 + c] + x_agg[n * 3 + c];
            x[n * 4 + c] = xn;
            if (outv) {
                if (bf) ((unsigned short*)outv)[NN * HD + n * 3 + c] = f2bf(xn);
                else ((float*)outv)[NN * HD + n * 3 + c] = xn;
            }
        }
    }

    s16x8 bw2[2][4];
#pragma unroll
    for (int kc = 0; kc < 2; ++kc)
#pragma unroll
        for (int nt = 0; nt < 4; ++nt)
#pragma unroll
            for (int j = 0; j < 8; ++j)
                bw2[kc][nt][j] = (short)f2bf(w2[(kc * 32 + q * 8 + j) * 64 + nt * 16 + l15]);

    float b1v[4], b2v[4];
#pragma unroll
    for (int nt = 0; nt < 4; ++nt) {
        b1v[nt] = b1[nt * 16 + l15];
        b2v[nt] = b2[nt * 16 + l15];
    }
    unsigned short* act = s_act[wid];

    for (int t = (blockIdx.x << 2) + wid; t < NT_N; t += gridDim.x << 2) {
        const int n = t * 16 + l15;
        const s16x8 a0 = *(const s16x8*)&h_bf[n * 64 + q * 8];
        const s16x8 a1 = *(const s16x8*)&h_bf[n * 64 + 32 + q * 8];
        const f32x4 m0 = *(const f32x4*)&m_agg[n * 64 + q * 8];
        const f32x4 m1 = *(const f32x4*)&m_agg[n * 64 + q * 8 + 4];
        const f32x4 m2 = *(const f32x4*)&m_agg[n * 64 + 32 + q * 8];
        const f32x4 m3 = *(const f32x4*)&m_agg[n * 64 + 32 + q * 8 + 4];
        s16x8 a2, a3;
#pragma unroll
        for (int j = 0; j < 4; ++j) {
            a2[j] = (short)f2bf(m0[j]); a2[4 + j] = (short)f2bf(m1[j]);
            a3[j] = (short)f2bf(m2[j]); a3[4 + j] = (short)f2bf(m3[j]);
        }

        f32x4 acc[4];
#pragma unroll
        for (int nt = 0; nt < 4; ++nt) acc[nt] = (f32x4){0.f, 0.f, 0.f, 0.f};
#pragma unroll
        for (int kc = 0; kc < 4; ++kc) {
            const s16x8 a = (kc == 0) ? a0 : (kc == 1) ? a1 : (kc == 2) ? a2 : a3;
#pragma unroll
            for (int nt = 0; nt < 4; ++nt) {
                const s16x8 b = *(const s16x8*)&s_w1p[((kc * 4 + nt) * 64 + lane) * 8];
                acc[nt] = __builtin_amdgcn_mfma_f32_16x16x32_bf16(a, b, acc[nt], 0, 0, 0);
            }
        }
#pragma unroll
        for (int nt = 0; nt < 4; ++nt)
#pragma unroll
            for (int r = 0; r < 4; ++r)
                act[(q * 4 + r) * ROWP + nt * 16 + l15] = f2bf_t(silu(acc[nt][r] + b1v[nt]));

        f32x4 acc2[4];
#pragma unroll
        for (int nt = 0; nt < 4; ++nt) acc2[nt] = (f32x4){0.f, 0.f, 0.f, 0.f};
#pragma unroll
        for (int kc = 0; kc < 2; ++kc) {
            const s16x8 a = *(const s16x8*)&act[l15 * ROWP + kc * 32 + q * 8];
#pragma unroll
            for (int nt = 0; nt < 4; ++nt)
                acc2[nt] = __builtin_amdgcn_mfma_f32_16x16x32_bf16(a, bw2[kc][nt], acc2[nt], 0, 0, 0);
        }
#pragma unroll
        for (int nt = 0; nt < 4; ++nt)
#pragma unroll
            for (int r = 0; r < 4; ++r) {
                const int row = t * 16 + q * 4 + r, col = nt * 16 + l15;
                const float hn = bf2f(h_bf[row * 64 + col]) + acc2[nt][r] + b2v[nt];
                h_bf[row * 64 + col] = f2bf(hn);
                if (outv) {
                    if (bf) ((unsigned short*)outv)[row * 64 + col] = f2bf(hn);
                    else ((float*)outv)[row * 64 + col] = hn;
                }
            }
    }
}

// -------------------------------------------------------------- launch ------
extern "C" void kernel_launch(void* const* d_in, const int* in_sizes, int n_in,
                              void* d_out, int out_size, void* d_ws, size_t ws_size,
                              hipStream_t stream) {
    const int* an = (const int*)d_in[0];
    const void* pos = d_in[1];
    const int* ei = (const int*)d_in[2];

    int wi = 4;
    if (n_in > 4 && in_sizes[4] == 6400) wi = 4;
    else if (n_in > 3 && in_sizes[3] == 6400) wi = 3;
    const void* emb = d_in[wi];
    const void* e_w1 = d_in[wi + 1];
    const void* e_b1 = d_in[wi + 2];
    const void* e_w2 = d_in[wi + 3];
    const void* e_b2 = d_in[wi + 4];
    const void* h_w1 = d_in[wi + 5];
    const void* h_b1 = d_in[wi + 6];
    const void* h_w2 = d_in[wi + 7];
    const void* h_b2 = d_in[wi + 8];
    const void* x_w1 = d_in[wi + 9];
    const void* x_b1 = d_in[wi + 10];
    const void* x_w2 = d_in[wi + 11];
    const void* x_b2 = d_in[wi + 12];

    float* ws = (float*)d_ws;
    int* flag = (int*)(ws + FLAG_OFF);
    float* wbuf = ws + WB_OFF;
    float* x = ws + X_OFF;
    float* m_agg = ws + MAGG_OFF;
    float* x_agg = ws + XAGG_OFF;
    unsigned short* h_bf = (unsigned short*)(ws + HBF_OFF);
    int* cnt = (int*)(ws + CNT_OFF);
    int* csum = (int*)(ws + CSUM_OFF);
    int* incl = (int*)(ws + INCL_OFF);
    int2* pair = (int2*)(ws + PAIR_OFF);

    detect_kernel<<<1, 64, 0, stream>>>((const unsigned short*)pos, flag);
    convert_kernel<<<256, 256, 0, stream>>>(pos, emb,
        e_w1, e_b1, e_w2, e_b2, h_w1, h_b1, h_w2, h_b2,
        x_w1, x_b1, x_w2, x_b2, wbuf, x, flag);
    init_h_kernel<<<784, 256, 0, stream>>>(an, wbuf + EMB_O, h_bf);

    hipMemsetAsync(cnt, 0, NCH * 256 * sizeof(int), stream);
    hist_kernel<<<512, 256, 0, stream>>>(ei, cnt);
    scan1_kernel<<<NCH, 256, 0, stream>>>(cnt, incl, csum);
    scan2_kernel<<<1, 256, 0, stream>>>(csum);
    scan3_kernel<<<NCH, 256, 0, stream>>>(cnt, incl, csum);
    scatter_kernel<<<512, 256, 0, stream>>>(ei, cnt, pair);

    for (int l = 0; l < NL; ++l) {
        hipMemsetAsync(m_agg, 0, (size_t)NN * HD * sizeof(float), stream);
        hipMemsetAsync(x_agg, 0, (size_t)NN * 3 * sizeof(float), stream);

        edge_mfma_kernel<<<1024, 256, 0, stream>>>(h_bf, x, pair,
            wbuf + EW1_O + l * 129 * 64, wbuf + EB1_O + l * 64,
            wbuf + EB2_O + l * 64,
            wbuf + EW2_O + l * 64 * 64,
            wbuf + XW1_O + l * 64 * 64, wbuf + XB1_O + l * 64,
            wbuf + XW2_O + l * 64, wbuf + XB2_O + l,
            m_agg, x_agg);

        void* out_p = (l == NL - 1) ? d_out : nullptr;
        node_mfma_kernel<<<782, 256, 0, stream>>>(x, m_agg, x_agg,
            wbuf + HW1_O + l * 128 * 64, wbuf + HB1_O + l * 64,
            wbuf + HW2_O + l * 64 * 64, wbuf + HB2_O + l * 64,
            h_bf, out_p, flag);
    }
}